// Round 5
// baseline (542.970 us; speedup 1.0000x reference)
//
#include <hip/hip_runtime.h>
#include <hip/hip_fp16.h>
#include <float.h>

#define DECAY 0.99f
#define OMD   0.01f
#define EPSF  1e-6f

constexpr int Bb = 8, Ss = 8192, Dd = 256, Kk = 2048;
constexpr int Nn = Bb * Ss;                 // 65536 rows

// ---- output layout (floats) ----
constexpr long OUT_QUANT = 0;                         // 16777216 floats
constexpr long OUT_IND   = (long)Nn * Dd;             // 16777216
constexpr long OUT_NCS   = OUT_IND + Nn;              // 16842752
constexpr long OUT_NEA   = OUT_NCS + Kk;              // 16844800
constexpr long OUT_NE    = OUT_NEA + (long)Kk * Dd;   // 17369088

// ---- workspace layout (floats) ----
constexpr long WS_COUNTS = 0;                         // K
constexpr long WS_TOTAL  = 2048;                      // 1
constexpr long WS_EE     = 2112;                      // K
constexpr long WS_BIG    = 4160;                      // embed_sum (atomic path)
                                                      // or 8 partials (ws path)
constexpr int  PARTS     = 8;                         // strip split for segsum
constexpr int  CODES     = 8;                         // codes per segsum block

typedef __attribute__((ext_vector_type(8))) short short8;
typedef __attribute__((ext_vector_type(8))) _Float16 half8;
typedef __attribute__((ext_vector_type(4))) float floatx4;

// fp16 single-pass certainty window: per-dist error std ~0.018, realistic max
// over all rows ~0.13; rows whose approx top-2 gap <= WINDOW get an exact
// fp32 rescan in pass 2. 0.5 = ~20 sigma margin. Also makes the cross-wave
// merge order tie-safe: any near-tie (<=WINDOW) is rescanned exactly.
#define WINDOW 0.5f

__device__ __forceinline__ ushort f2h(float v)
{
    __half h = __float2half(v);
    return *(ushort*)&h;
}

// ============================================================
// Kernel B: embed -> e_h (fp16) and ee[k] = sum_d embed[k][d]^2 (fp32 exact)
// ============================================================
__global__ __launch_bounds__(256) void convert_e_kernel(
    const float* __restrict__ embed, ushort* __restrict__ e_h,
    float* __restrict__ ee)
{
    int row  = blockIdx.x * 4 + (threadIdx.x >> 6);
    int lane = threadIdx.x & 63;
    long base = (long)row * Dd + lane * 4;
    float4 v = *(const float4*)&embed[base];
    float s = v.x * v.x + v.y * v.y + v.z * v.z + v.w * v.w;
    ushort4 h;
    h.x = f2h(v.x); h.y = f2h(v.y); h.z = f2h(v.z); h.w = f2h(v.w);
    *(ushort4*)&e_h[base] = h;
    #pragma unroll
    for (int off = 32; off >= 1; off >>= 1)
        s += __shfl_xor(s, off, 64);
    if (lane == 0) ee[row] = s;
}

// ============================================================
// Kernel C (pass 1): fp16 MFMA distance + top-2 argmin.
//
// v6 (round 5): barrier-free streaming dataflow.
//  * Block = 4 waves, tile = 64 rows x ALL 2048 codes. x rows loaded ONCE
//    (fp32 coalesced, fused fp16 convert -> swizzled 32KB LDS tile);
//    convert_x kernel deleted; zero x re-reads.
//  * Main loop has NO barriers and NO staging: B fragments load directly
//    from global e_h (1MB, L2-resident). Each half8 wave-load covers
//    exactly 16 full 64B lines (perfect coalescing).
//  * A-LDS swizzle: 16B chunk c of row r stored at slot c ^ (r&7) ->
//    frag reads stay at the conflict-free b128 baseline.
//  * ~170 VGPR -> 3 waves/EU; LDS 35KB -> 3 blocks/CU resident.
// ============================================================
__global__ __launch_bounds__(256) void pass1_kernel(
    const float* __restrict__ x, const ushort* __restrict__ e_h,
    const float* __restrict__ ee, float* __restrict__ ind_out,
    int* __restrict__ qbase)
{
    __shared__ __attribute__((aligned(16))) ushort as[64 * 256];   // 32KB
    __shared__ float redv[4][64];
    __shared__ float red2[4][64];
    __shared__ int   redi[4][64];

    const int tid  = threadIdx.x;
    const int lane = tid & 63;
    const int quad = lane >> 4;
    const int l15  = lane & 15;
    const int w    = tid >> 6;
    const long row0 = (long)blockIdx.x * 64;

    // ---- prologue: x fp32 -> fp16 swizzled LDS (one time) ----
    // li = float4 index; row r = li>>6, col c = (li&63)*4 (floats==halves).
    // wave w writes row i*4+w fully per iter: conflict-free contiguous row.
    #pragma unroll
    for (int i = 0; i < 16; ++i) {
        int li = i * 256 + tid;
        int r  = li >> 6;
        int c  = (li & 63) * 4;
        float4 v = *(const float4*)&x[row0 * Dd + (long)li * 4];
        ushort4 h;
        h.x = f2h(v.x); h.y = f2h(v.y); h.z = f2h(v.z); h.w = f2h(v.w);
        int slot = (c >> 3) ^ (r & 7);
        *(ushort4*)&as[r * 256 + slot * 8 + (c & 7)] = h;
    }
    __syncthreads();

    float bestv[16], best2v[16];
    int   besti[16];
    #pragma unroll
    for (int i = 0; i < 16; ++i) { bestv[i] = FLT_MAX; best2v[i] = FLT_MAX; besti[i] = 0; }

    for (int ct = 0; ct < Kk / 256; ++ct) {
        floatx4 acc[4][4];
        #pragma unroll
        for (int rt = 0; rt < 4; ++rt)
            #pragma unroll
            for (int jt = 0; jt < 4; ++jt)
                acc[rt][jt] = (floatx4){0.f, 0.f, 0.f, 0.f};

        // per-jt code / base address (constant over ks)
        const int cbase = ct * 256 + w * 64 + l15;

        #pragma unroll
        for (int ks = 0; ks < 8; ++ks) {
            half8 af[4];
            #pragma unroll
            for (int rt = 0; rt < 4; ++rt) {
                int chunk = ks * 4 + quad;
                af[rt] = *(const half8*)&as[(rt * 16 + l15) * 256 +
                                            ((chunk ^ (l15 & 7)) << 3)];
            }
            #pragma unroll
            for (int jt = 0; jt < 4; ++jt) {
                const ushort* bp = &e_h[((long)(cbase + jt * 16) << 8) +
                                        ks * 32 + quad * 8];
                half8 bf = *(const half8*)bp;
                #pragma unroll
                for (int rt = 0; rt < 4; ++rt)
                    acc[rt][jt] = __builtin_amdgcn_mfma_f32_16x16x32_f16(
                        af[rt], bf, acc[rt][jt], 0, 0, 0);
            }
        }

        #pragma unroll
        for (int jt = 0; jt < 4; ++jt) {
            int c = ct * 256 + w * 64 + jt * 16 + l15;
            float eec = ee[c];
            #pragma unroll
            for (int rt = 0; rt < 4; ++rt) {
                #pragma unroll
                for (int reg = 0; reg < 4; ++reg) {
                    float s = eec - 2.0f * acc[rt][jt][reg];
                    int slot = rt * 4 + reg;
                    if (s < bestv[slot]) {
                        best2v[slot] = bestv[slot];
                        bestv[slot] = s; besti[slot] = c;
                    } else {
                        best2v[slot] = fminf(best2v[slot], s);
                    }
                }
            }
        }
    }

    // 16-lane top-2 reduce (cols within wave partition)
    #pragma unroll
    for (int slot = 0; slot < 16; ++slot) {
        float bv = bestv[slot]; int bi = besti[slot]; float b2 = best2v[slot];
        #pragma unroll
        for (int off = 8; off >= 1; off >>= 1) {
            float ov  = __shfl_xor(bv, off, 16);
            int   oi  = __shfl_xor(bi, off, 16);
            float ov2 = __shfl_xor(b2, off, 16);
            float nm2 = fminf(fminf(b2, ov2), fmaxf(bv, ov));
            if (ov < bv) { bv = ov; bi = oi; }
            b2 = nm2;
        }
        bestv[slot] = bv; besti[slot] = bi; best2v[slot] = b2;
    }

    if (l15 == 0) {
        #pragma unroll
        for (int rt = 0; rt < 4; ++rt)
            #pragma unroll
            for (int reg = 0; reg < 4; ++reg) {
                int rloc = rt * 16 + quad * 4 + reg;   // 0..63
                int slot = rt * 4 + reg;
                redv[w][rloc] = bestv[slot];
                red2[w][rloc] = best2v[slot];
                redi[w][rloc] = besti[slot];
            }
    }
    __syncthreads();

    // cross-wave merge of 4 disjoint code partitions; tie order is safe
    // (near-ties <= WINDOW go to pass2's exact lowest-index rescan).
    if (tid < 64) {
        float v[4], s2[4]; int ix[4];
        #pragma unroll
        for (int p = 0; p < 4; ++p) {
            v[p] = redv[p][tid]; s2[p] = red2[p][tid]; ix[p] = redi[p][tid];
        }
        float m1 = v[0]; int mi = ix[0]; int arg = 0;
        #pragma unroll
        for (int p = 1; p < 4; ++p)
            if (v[p] < m1) { m1 = v[p]; mi = ix[p]; arg = p; }
        float m2 = FLT_MAX;
        #pragma unroll
        for (int p = 0; p < 4; ++p) {
            m2 = fminf(m2, s2[p]);
            if (p != arg) m2 = fminf(m2, v[p]);
        }
        long rowAbs = row0 + tid;
        ind_out[rowAbs] = (float)mi;
        if (m2 - m1 <= WINDOW) {
            int q = atomicAdd(qbase, 1);
            qbase[1 + q] = (int)rowAbs;
        }
    }
}

// ============================================================
// Kernel D (pass 2): exact fp32 rescan of ambiguous rows (8-row batches).
// ============================================================
constexpr int RB = 8;
__global__ __launch_bounds__(256) void pass2_kernel(
    const float* __restrict__ x, const float* __restrict__ embed,
    const float* __restrict__ ee, const int* __restrict__ qbase,
    float* __restrict__ ind_out)
{
    __shared__ float xs[RB][256];
    __shared__ float sv[RB][256];
    __shared__ int   si[RB][256];
    const int tid = threadIdx.x;
    const int count = qbase[0];

    for (int q0 = blockIdx.x * RB; q0 < count; q0 += gridDim.x * RB) {
        const int nr = (count - q0 < RB) ? (count - q0) : RB;
        __syncthreads();
        for (int r = 0; r < nr; ++r)
            xs[r][tid] = x[(long)qbase[1 + q0 + r] * Dd + tid];
        __syncthreads();

        float bv[RB]; int bi[RB];
        #pragma unroll
        for (int r = 0; r < RB; ++r) { bv[r] = FLT_MAX; bi[r] = 0; }

        for (int i = 0; i < Kk / 256; ++i) {
            const int c = i * 256 + tid;
            const float4* er = (const float4*)&embed[(long)c * Dd];
            float dot[RB];
            #pragma unroll
            for (int r = 0; r < RB; ++r) dot[r] = 0.0f;
            for (int d = 0; d < Dd / 4; ++d) {
                float4 e4 = er[d];
                #pragma unroll
                for (int r = 0; r < RB; ++r) {
                    float4 x4 = *(const float4*)&xs[r][d * 4];
                    dot[r] += e4.x * x4.x + e4.y * x4.y + e4.z * x4.z + e4.w * x4.w;
                }
            }
            float eec = ee[c];
            #pragma unroll
            for (int r = 0; r < RB; ++r) {
                float s = eec - 2.0f * dot[r];
                if (s < bv[r]) { bv[r] = s; bi[r] = c; }
            }
        }

        #pragma unroll
        for (int r = 0; r < RB; ++r) { sv[r][tid] = bv[r]; si[r][tid] = bi[r]; }
        __syncthreads();
        for (int off = 128; off >= 1; off >>= 1) {
            if (tid < off) {
                #pragma unroll
                for (int r = 0; r < RB; ++r) {
                    float v2 = sv[r][tid + off]; int i2 = si[r][tid + off];
                    if (v2 < sv[r][tid] || (v2 == sv[r][tid] && i2 < si[r][tid])) {
                        sv[r][tid] = v2; si[r][tid] = i2;
                    }
                }
            }
            __syncthreads();
        }
        if (tid < nr)
            ind_out[qbase[1 + q0 + tid]] = (float)si[tid][0];
        __syncthreads();
    }
}

// ============================================================
// Kernel E: quantize gather (pure BW, no atomics). One wave per row.
// ============================================================
__global__ __launch_bounds__(256) void quant_gather_kernel(
    const float* __restrict__ embed, const float* __restrict__ ind_f,
    float* __restrict__ quant)
{
    long row  = (long)blockIdx.x * 4 + (threadIdx.x >> 6);
    int  lane = threadIdx.x & 63;
    int  idx  = (int)ind_f[row];
    float4 ev = *(const float4*)&embed[(long)idx * Dd + lane * 4];
    *(float4*)&quant[row * Dd + lane * 4] = ev;
}

// ============================================================
// Kernel F: pull-based segmented sum, CODES=8 codes per block.
// ============================================================
template <int USE_ATOMIC>
__global__ __launch_bounds__(256) void segsum_kernel(
    const float* __restrict__ x, const float* __restrict__ ind_f,
    float* __restrict__ dst, float* __restrict__ counts)
{
    __shared__ float part[CODES][4][256];   // 32KB
    __shared__ float cnt_l[CODES][4];
    const int tid  = threadIdx.x;
    const int w    = tid >> 6;
    const int lane = tid & 63;
    const int k0   = (blockIdx.x >> 3) * CODES;
    const int s    = blockIdx.x & 7;

    constexpr int STRIP = Nn / PARTS;          // 8192 rows
    constexpr int WAVE_ROWS = STRIP / 4;       // 2048 rows per wave
    const int base0 = s * STRIP + w * WAVE_ROWS;

    float4 acc[CODES];
    int    cnt[CODES];
    #pragma unroll
    for (int c = 0; c < CODES; ++c) { acc[c] = (float4){0.f,0.f,0.f,0.f}; cnt[c] = 0; }

    for (int win = 0; win < WAVE_ROWS; win += 64) {
        int idx = (int)ind_f[base0 + win + lane];
        unsigned rel = (unsigned)(idx - k0);
        unsigned long long m = __ballot(rel < (unsigned)CODES);
        while (m) {
            int l = __ffsll((unsigned long long)m) - 1;
            m &= m - 1;
            int code = __shfl((int)rel, l, 64);   // wave-uniform
            long row = base0 + win + l;
            float4 v = *(const float4*)&x[row * Dd + lane * 4];
            switch (code) {
                case 0: acc[0].x+=v.x; acc[0].y+=v.y; acc[0].z+=v.z; acc[0].w+=v.w; cnt[0]++; break;
                case 1: acc[1].x+=v.x; acc[1].y+=v.y; acc[1].z+=v.z; acc[1].w+=v.w; cnt[1]++; break;
                case 2: acc[2].x+=v.x; acc[2].y+=v.y; acc[2].z+=v.z; acc[2].w+=v.w; cnt[2]++; break;
                case 3: acc[3].x+=v.x; acc[3].y+=v.y; acc[3].z+=v.z; acc[3].w+=v.w; cnt[3]++; break;
                case 4: acc[4].x+=v.x; acc[4].y+=v.y; acc[4].z+=v.z; acc[4].w+=v.w; cnt[4]++; break;
                case 5: acc[5].x+=v.x; acc[5].y+=v.y; acc[5].z+=v.z; acc[5].w+=v.w; cnt[5]++; break;
                case 6: acc[6].x+=v.x; acc[6].y+=v.y; acc[6].z+=v.z; acc[6].w+=v.w; cnt[6]++; break;
                case 7: acc[7].x+=v.x; acc[7].y+=v.y; acc[7].z+=v.z; acc[7].w+=v.w; cnt[7]++; break;
            }
        }
    }

    #pragma unroll
    for (int c = 0; c < CODES; ++c) {
        *(float4*)&part[c][w][lane * 4] = acc[c];
        if (lane == 0) cnt_l[c][w] = (float)cnt[c];
    }
    __syncthreads();

    #pragma unroll
    for (int c = 0; c < CODES; ++c) {
        float sum = part[c][0][tid] + part[c][1][tid] + part[c][2][tid] + part[c][3][tid];
        if (USE_ATOMIC) {
            if (sum != 0.0f) atomicAdd(&dst[(long)(k0 + c) * Dd + tid], sum);
        } else {
            dst[((long)s * Kk + (k0 + c)) * Dd + tid] = sum;
        }
    }
    if (tid < CODES)
        atomicAdd(&counts[k0 + tid],
                  cnt_l[tid][0] + cnt_l[tid][1] + cnt_l[tid][2] + cnt_l[tid][3]);
}

// ============================================================
// Kernel G: new_cluster_size + total (single block)
// ============================================================
__global__ __launch_bounds__(256) void ema_cs_kernel(
    const float* __restrict__ cs, const float* __restrict__ counts,
    float* __restrict__ ncs, float* __restrict__ total_ws)
{
    __shared__ float red[256];
    int tid = threadIdx.x;
    float s = 0.0f;
    #pragma unroll
    for (int i = 0; i < 8; ++i) {
        int k = tid + i * 256;
        float v = cs[k] * DECAY + OMD * counts[k];
        ncs[k] = v;
        s += v;
    }
    red[tid] = s;
    __syncthreads();
    #pragma unroll
    for (int off = 128; off >= 1; off >>= 1) {
        if (tid < off) red[tid] += red[tid + off];
        __syncthreads();
    }
    if (tid == 0) total_ws[0] = red[0];
}

// ============================================================
// Kernel H: combine partials -> embed_sum; nea; ne.
// ============================================================
__global__ __launch_bounds__(256) void nea_ne_kernel(
    const float* __restrict__ ea, const float* __restrict__ partials,
    int nparts, const float* __restrict__ ncs, const float* __restrict__ total_ws,
    float* __restrict__ nea, float* __restrict__ ne)
{
    long g = ((long)blockIdx.x * 256 + threadIdx.x) * 4;
    int  k = (int)(g >> 8);
    int  d = (int)(g & 255);

    float4 sv = {0.f, 0.f, 0.f, 0.f};
    for (int p = 0; p < nparts; ++p) {
        float4 pv = *(const float4*)&partials[((long)p * Kk + k) * Dd + d];
        sv.x += pv.x; sv.y += pv.y; sv.z += pv.z; sv.w += pv.w;
    }

    float4 av = *(const float4*)&ea[g];
    float4 out_nea;
    out_nea.x = av.x * DECAY + OMD * sv.x;
    out_nea.y = av.y * DECAY + OMD * sv.y;
    out_nea.z = av.z * DECAY + OMD * sv.z;
    out_nea.w = av.w * DECAY + OMD * sv.w;
    *(float4*)&nea[g] = out_nea;

    float total = total_ws[0];
    float sm = (ncs[k] + EPSF) / (total + EPSF * (float)Kk) * total;
    float inv = 1.0f / sm;
    float4 out_ne;
    out_ne.x = out_nea.x * inv;
    out_ne.y = out_nea.y * inv;
    out_ne.z = out_nea.z * inv;
    out_ne.w = out_nea.w * inv;
    *(float4*)&ne[g] = out_ne;
}

// ============================================================
extern "C" void kernel_launch(void* const* d_in, const int* in_sizes, int n_in,
                              void* d_out, int out_size, void* d_ws, size_t ws_size,
                              hipStream_t stream)
{
    const float* x     = (const float*)d_in[0];
    const float* embed = (const float*)d_in[1];
    const float* cs    = (const float*)d_in[2];
    const float* ea    = (const float*)d_in[3];

    float* out   = (float*)d_out;
    float* quant = out + OUT_QUANT;
    float* ind_f = out + OUT_IND;
    float* ncs   = out + OUT_NCS;
    float* nea   = out + OUT_NEA;
    float* ne    = out + OUT_NE;

    float* ws     = (float*)d_ws;
    float* counts = ws + WS_COUNTS;
    float* total  = ws + WS_TOTAL;
    float* ee     = ws + WS_EE;
    float* big    = ws + WS_BIG;     // embed_sum (atomic) or partials (ws path)

    // scratch inside d_out
    ushort* e_h = (ushort*)(out + OUT_NEA);     // 1MB fp16, nea region
    int*    qb  = (int*)(out + OUT_NE);

    const size_t need_partials =
        (size_t)(WS_BIG + (long)PARTS * Kk * Dd) * sizeof(float) + 1024;
    const bool use_ws_partials = ws_size >= need_partials;

    hipMemsetAsync(counts, 0, Kk * sizeof(float), stream);
    hipMemsetAsync(qb, 0, sizeof(int), stream);
    if (!use_ws_partials)
        hipMemsetAsync(big, 0, (size_t)Kk * Dd * sizeof(float), stream);

    convert_e_kernel<<<Kk / 4, 256, 0, stream>>>(embed, e_h, ee);
    pass1_kernel<<<Nn / 64, 256, 0, stream>>>(x, e_h, ee, ind_f, qb);
    pass2_kernel<<<512, 256, 0, stream>>>(x, embed, ee, qb, ind_f);
    quant_gather_kernel<<<Nn / 4, 256, 0, stream>>>(embed, ind_f, quant);
    if (use_ws_partials)
        segsum_kernel<0><<<(Kk / CODES) * PARTS, 256, 0, stream>>>(x, ind_f, big, counts);
    else
        segsum_kernel<1><<<(Kk / CODES) * PARTS, 256, 0, stream>>>(x, ind_f, big, counts);
    ema_cs_kernel<<<1, 256, 0, stream>>>(cs, counts, ncs, total);
    nea_ne_kernel<<<(Kk * Dd / 4) / 256, 256, 0, stream>>>(
        ea, big, use_ws_partials ? PARTS : 1, ncs, total, nea, ne);
}

// Round 6
// 447.626 us; speedup vs baseline: 1.2130x; 1.2130x over previous
//
#include <hip/hip_runtime.h>
#include <hip/hip_fp16.h>
#include <float.h>

#define DECAY 0.99f
#define OMD   0.01f
#define EPSF  1e-6f

constexpr int Bb = 8, Ss = 8192, Dd = 256, Kk = 2048;
constexpr int Nn = Bb * Ss;                 // 65536 rows

// ---- output layout (floats) ----
constexpr long OUT_QUANT = 0;                         // 16777216 floats
constexpr long OUT_IND   = (long)Nn * Dd;             // 16777216
constexpr long OUT_NCS   = OUT_IND + Nn;              // 16842752
constexpr long OUT_NEA   = OUT_NCS + Kk;              // 16844800
constexpr long OUT_NE    = OUT_NEA + (long)Kk * Dd;   // 17369088

// ---- workspace layout (floats) ----
constexpr long WS_COUNTS = 0;                         // K
constexpr long WS_TOTAL  = 2048;                      // 1
constexpr long WS_EE     = 2112;                      // K
constexpr long WS_BIG    = 4160;                      // embed_sum (atomic path)
                                                      // or 8 partials (ws path)
constexpr int  PARTS     = 8;                         // strip split for segsum
constexpr int  CODES     = 8;                         // codes per segsum block

typedef __attribute__((ext_vector_type(8))) short short8;
typedef __attribute__((ext_vector_type(8))) _Float16 half8;
typedef __attribute__((ext_vector_type(4))) float floatx4;

// fp16 single-pass certainty window: per-dist error std ~0.018, realistic max
// over all rows ~0.13; rows whose approx top-2 gap <= WINDOW get an exact
// fp32 rescan in pass 2. 0.5 = ~20 sigma margin. Also makes the cross-wave
// merge order tie-safe: any near-tie (<=WINDOW) is rescanned exactly.
#define WINDOW 0.5f

__device__ __forceinline__ ushort f2h(float v)
{
    __half h = __float2half(v);
    return *(ushort*)&h;
}

// ============================================================
// Kernel B: embed -> e_h (fp16), ee[k] = sum_d embed[k][d]^2, and
// (block 0) reset the pass-2 ambiguity queue counter.
// ============================================================
__global__ __launch_bounds__(256) void convert_e_kernel(
    const float* __restrict__ embed, ushort* __restrict__ e_h,
    float* __restrict__ ee, int* __restrict__ qbase)
{
    if (blockIdx.x == 0 && threadIdx.x == 0) qbase[0] = 0;
    int row  = blockIdx.x * 4 + (threadIdx.x >> 6);
    int lane = threadIdx.x & 63;
    long base = (long)row * Dd + lane * 4;
    float4 v = *(const float4*)&embed[base];
    float s = v.x * v.x + v.y * v.y + v.z * v.z + v.w * v.w;
    ushort4 h;
    h.x = f2h(v.x); h.y = f2h(v.y); h.z = f2h(v.z); h.w = f2h(v.w);
    *(ushort4*)&e_h[base] = h;
    #pragma unroll
    for (int off = 32; off >= 1; off >>= 1)
        s += __shfl_xor(s, off, 64);
    if (lane == 0) ee[row] = s;
}

// ============================================================
// Kernel C (pass 1): fp16 MFMA distance + top-2 argmin + fused quant gather.
//
// v7 (round 6): round-5 streaming structure with the occupancy cliff fixed.
//  * Round-5 failure: 200 VGPR + 64 AGPR acc = 264 > 256 -> 1 wave/EU,
//    latency-bound at MfmaUtil 11%. Fix: jt 4->2 (wave covers 32 codes/ct
//    over 16 cts) -> acc 32 AGPRs, VGPR ~140 -> 2 waves/EU (pinned).
//  * Still barrier-free in the K loop: A tile (64 rows) resident in
//    swizzled LDS (x read ONCE, fused fp32->fp16 convert); B fragments
//    stream directly from L2-resident e_h (1 MB), each wave load = 16
//    full 64B lines, perfectly coalesced. Compiler free to pipeline
//    loads deep across ks/jt (no barriers, reg headroom).
//  * Fused epilogue: block gathers embed[ind] -> quant for its 64 rows
//    (deletes the separate quant_gather kernel; pass2 rewrites queued rows).
// ============================================================
__global__ __attribute__((amdgpu_waves_per_eu(2, 2))) __launch_bounds__(256)
void pass1_kernel(
    const float* __restrict__ x, const ushort* __restrict__ e_h,
    const float* __restrict__ embed, const float* __restrict__ ee,
    float* __restrict__ ind_out, float* __restrict__ quant,
    int* __restrict__ qbase)
{
    __shared__ __attribute__((aligned(16))) ushort as[64 * 256];   // 32KB
    __shared__ float redv[4][64];
    __shared__ float red2[4][64];
    __shared__ int   redi[4][64];

    const int tid  = threadIdx.x;
    const int lane = tid & 63;
    const int quad = lane >> 4;
    const int l15  = lane & 15;
    const int w    = tid >> 6;
    const long row0 = (long)blockIdx.x * 64;

    // ---- prologue: x fp32 -> fp16 swizzled LDS (one time) ----
    #pragma unroll
    for (int i = 0; i < 16; ++i) {
        int li = i * 256 + tid;
        int r  = li >> 6;
        int c  = (li & 63) * 4;
        float4 v = *(const float4*)&x[row0 * Dd + (long)li * 4];
        ushort4 h;
        h.x = f2h(v.x); h.y = f2h(v.y); h.z = f2h(v.z); h.w = f2h(v.w);
        int slot = (c >> 3) ^ (r & 7);
        *(ushort4*)&as[r * 256 + slot * 8 + (c & 7)] = h;
    }
    __syncthreads();

    float bestv[16], best2v[16];
    int   besti[16];
    #pragma unroll
    for (int i = 0; i < 16; ++i) { bestv[i] = FLT_MAX; best2v[i] = FLT_MAX; besti[i] = 0; }

    for (int ct = 0; ct < Kk / 128; ++ct) {
        floatx4 acc[4][2];
        #pragma unroll
        for (int rt = 0; rt < 4; ++rt)
            #pragma unroll
            for (int jt = 0; jt < 2; ++jt)
                acc[rt][jt] = (floatx4){0.f, 0.f, 0.f, 0.f};

        const int cbase = ct * 128 + w * 32 + l15;

        #pragma unroll
        for (int ks = 0; ks < 8; ++ks) {
            half8 af[4];
            #pragma unroll
            for (int rt = 0; rt < 4; ++rt) {
                int chunk = ks * 4 + quad;
                af[rt] = *(const half8*)&as[(rt * 16 + l15) * 256 +
                                            ((chunk ^ (l15 & 7)) << 3)];
            }
            #pragma unroll
            for (int jt = 0; jt < 2; ++jt) {
                const ushort* bp = &e_h[((long)(cbase + jt * 16) << 8) +
                                        ks * 32 + quad * 8];
                half8 bf = *(const half8*)bp;
                #pragma unroll
                for (int rt = 0; rt < 4; ++rt)
                    acc[rt][jt] = __builtin_amdgcn_mfma_f32_16x16x32_f16(
                        af[rt], bf, acc[rt][jt], 0, 0, 0);
            }
        }

        #pragma unroll
        for (int jt = 0; jt < 2; ++jt) {
            int c = ct * 128 + w * 32 + jt * 16 + l15;
            float eec = ee[c];
            #pragma unroll
            for (int rt = 0; rt < 4; ++rt) {
                #pragma unroll
                for (int reg = 0; reg < 4; ++reg) {
                    float s = eec - 2.0f * acc[rt][jt][reg];
                    int slot = rt * 4 + reg;
                    if (s < bestv[slot]) {
                        best2v[slot] = bestv[slot];
                        bestv[slot] = s; besti[slot] = c;
                    } else {
                        best2v[slot] = fminf(best2v[slot], s);
                    }
                }
            }
        }
    }

    // 16-lane top-2 reduce (cols within wave partition)
    #pragma unroll
    for (int slot = 0; slot < 16; ++slot) {
        float bv = bestv[slot]; int bi = besti[slot]; float b2 = best2v[slot];
        #pragma unroll
        for (int off = 8; off >= 1; off >>= 1) {
            float ov  = __shfl_xor(bv, off, 16);
            int   oi  = __shfl_xor(bi, off, 16);
            float ov2 = __shfl_xor(b2, off, 16);
            float nm2 = fminf(fminf(b2, ov2), fmaxf(bv, ov));
            if (ov < bv) { bv = ov; bi = oi; }
            b2 = nm2;
        }
        bestv[slot] = bv; besti[slot] = bi; best2v[slot] = b2;
    }

    if (l15 == 0) {
        #pragma unroll
        for (int rt = 0; rt < 4; ++rt)
            #pragma unroll
            for (int reg = 0; reg < 4; ++reg) {
                int rloc = rt * 16 + quad * 4 + reg;   // 0..63
                int slot = rt * 4 + reg;
                redv[w][rloc] = bestv[slot];
                red2[w][rloc] = best2v[slot];
                redi[w][rloc] = besti[slot];
            }
    }
    __syncthreads();

    // cross-wave merge of 4 disjoint code partitions; tie order is safe
    // (near-ties <= WINDOW go to pass2's exact lowest-index rescan).
    if (tid < 64) {
        float v[4], s2[4]; int ix[4];
        #pragma unroll
        for (int p = 0; p < 4; ++p) {
            v[p] = redv[p][tid]; s2[p] = red2[p][tid]; ix[p] = redi[p][tid];
        }
        float m1 = v[0]; int mi = ix[0]; int arg = 0;
        #pragma unroll
        for (int p = 1; p < 4; ++p)
            if (v[p] < m1) { m1 = v[p]; mi = ix[p]; arg = p; }
        float m2 = FLT_MAX;
        #pragma unroll
        for (int p = 0; p < 4; ++p) {
            m2 = fminf(m2, s2[p]);
            if (p != arg) m2 = fminf(m2, v[p]);
        }
        long rowAbs = row0 + tid;
        ind_out[rowAbs] = (float)mi;
        redi[0][tid] = mi;           // publish for fused quant gather
        if (m2 - m1 <= WINDOW) {
            int q = atomicAdd(qbase, 1);
            qbase[1 + q] = (int)rowAbs;
        }
    }
    __syncthreads();

    // ---- fused quant gather: quant[row] = embed[ind[row]] ----
    // wave w handles rows w*16..w*16+15; embed is L2-resident (2MB).
    #pragma unroll
    for (int rr = 0; rr < 16; ++rr) {
        int row = w * 16 + rr;
        int idx = redi[0][row];
        float4 ev = *(const float4*)&embed[(long)idx * Dd + lane * 4];
        *(float4*)&quant[(row0 + row) * Dd + lane * 4] = ev;
    }
}

// ============================================================
// Kernel D (pass 2): exact fp32 rescan of ambiguous rows (8-row batches),
// now also rewriting quant for every queued row (keeps fused-quant correct).
// ============================================================
constexpr int RB = 8;
__global__ __launch_bounds__(256) void pass2_kernel(
    const float* __restrict__ x, const float* __restrict__ embed,
    const float* __restrict__ ee, const int* __restrict__ qbase,
    float* __restrict__ ind_out, float* __restrict__ quant)
{
    __shared__ float xs[RB][256];
    __shared__ float sv[RB][256];
    __shared__ int   si[RB][256];
    const int tid = threadIdx.x;
    const int count = qbase[0];

    for (int q0 = blockIdx.x * RB; q0 < count; q0 += gridDim.x * RB) {
        const int nr = (count - q0 < RB) ? (count - q0) : RB;
        __syncthreads();
        for (int r = 0; r < nr; ++r)
            xs[r][tid] = x[(long)qbase[1 + q0 + r] * Dd + tid];
        __syncthreads();

        float bv[RB]; int bi[RB];
        #pragma unroll
        for (int r = 0; r < RB; ++r) { bv[r] = FLT_MAX; bi[r] = 0; }

        for (int i = 0; i < Kk / 256; ++i) {
            const int c = i * 256 + tid;
            const float4* er = (const float4*)&embed[(long)c * Dd];
            float dot[RB];
            #pragma unroll
            for (int r = 0; r < RB; ++r) dot[r] = 0.0f;
            for (int d = 0; d < Dd / 4; ++d) {
                float4 e4 = er[d];
                #pragma unroll
                for (int r = 0; r < RB; ++r) {
                    float4 x4 = *(const float4*)&xs[r][d * 4];
                    dot[r] += e4.x * x4.x + e4.y * x4.y + e4.z * x4.z + e4.w * x4.w;
                }
            }
            float eec = ee[c];
            #pragma unroll
            for (int r = 0; r < RB; ++r) {
                float s = eec - 2.0f * dot[r];
                if (s < bv[r]) { bv[r] = s; bi[r] = c; }
            }
        }

        #pragma unroll
        for (int r = 0; r < RB; ++r) { sv[r][tid] = bv[r]; si[r][tid] = bi[r]; }
        __syncthreads();
        for (int off = 128; off >= 1; off >>= 1) {
            if (tid < off) {
                #pragma unroll
                for (int r = 0; r < RB; ++r) {
                    float v2 = sv[r][tid + off]; int i2 = si[r][tid + off];
                    if (v2 < sv[r][tid] || (v2 == sv[r][tid] && i2 < si[r][tid])) {
                        sv[r][tid] = v2; si[r][tid] = i2;
                    }
                }
            }
            __syncthreads();
        }
        if (tid < nr)
            ind_out[qbase[1 + q0 + tid]] = (float)si[tid][0];
        // rewrite quant for queued rows (exact final index)
        for (int r = 0; r < nr; ++r) {
            int code = si[r][0];
            long row = qbase[1 + q0 + r];
            quant[row * Dd + tid] = embed[(long)code * Dd + tid];
        }
        __syncthreads();
    }
}

// ============================================================
// Kernel F: pull-based segmented sum, CODES=8 codes per block.
// ============================================================
template <int USE_ATOMIC>
__global__ __launch_bounds__(256) void segsum_kernel(
    const float* __restrict__ x, const float* __restrict__ ind_f,
    float* __restrict__ dst, float* __restrict__ counts)
{
    __shared__ float part[CODES][4][256];   // 32KB
    __shared__ float cnt_l[CODES][4];
    const int tid  = threadIdx.x;
    const int w    = tid >> 6;
    const int lane = tid & 63;
    const int k0   = (blockIdx.x >> 3) * CODES;
    const int s    = blockIdx.x & 7;

    constexpr int STRIP = Nn / PARTS;          // 8192 rows
    constexpr int WAVE_ROWS = STRIP / 4;       // 2048 rows per wave
    const int base0 = s * STRIP + w * WAVE_ROWS;

    float4 acc[CODES];
    int    cnt[CODES];
    #pragma unroll
    for (int c = 0; c < CODES; ++c) { acc[c] = (float4){0.f,0.f,0.f,0.f}; cnt[c] = 0; }

    for (int win = 0; win < WAVE_ROWS; win += 64) {
        int idx = (int)ind_f[base0 + win + lane];
        unsigned rel = (unsigned)(idx - k0);
        unsigned long long m = __ballot(rel < (unsigned)CODES);
        while (m) {
            int l = __ffsll((unsigned long long)m) - 1;
            m &= m - 1;
            int code = __shfl((int)rel, l, 64);   // wave-uniform
            long row = base0 + win + l;
            float4 v = *(const float4*)&x[row * Dd + lane * 4];
            switch (code) {
                case 0: acc[0].x+=v.x; acc[0].y+=v.y; acc[0].z+=v.z; acc[0].w+=v.w; cnt[0]++; break;
                case 1: acc[1].x+=v.x; acc[1].y+=v.y; acc[1].z+=v.z; acc[1].w+=v.w; cnt[1]++; break;
                case 2: acc[2].x+=v.x; acc[2].y+=v.y; acc[2].z+=v.z; acc[2].w+=v.w; cnt[2]++; break;
                case 3: acc[3].x+=v.x; acc[3].y+=v.y; acc[3].z+=v.z; acc[3].w+=v.w; cnt[3]++; break;
                case 4: acc[4].x+=v.x; acc[4].y+=v.y; acc[4].z+=v.z; acc[4].w+=v.w; cnt[4]++; break;
                case 5: acc[5].x+=v.x; acc[5].y+=v.y; acc[5].z+=v.z; acc[5].w+=v.w; cnt[5]++; break;
                case 6: acc[6].x+=v.x; acc[6].y+=v.y; acc[6].z+=v.z; acc[6].w+=v.w; cnt[6]++; break;
                case 7: acc[7].x+=v.x; acc[7].y+=v.y; acc[7].z+=v.z; acc[7].w+=v.w; cnt[7]++; break;
            }
        }
    }

    #pragma unroll
    for (int c = 0; c < CODES; ++c) {
        *(float4*)&part[c][w][lane * 4] = acc[c];
        if (lane == 0) cnt_l[c][w] = (float)cnt[c];
    }
    __syncthreads();

    #pragma unroll
    for (int c = 0; c < CODES; ++c) {
        float sum = part[c][0][tid] + part[c][1][tid] + part[c][2][tid] + part[c][3][tid];
        if (USE_ATOMIC) {
            if (sum != 0.0f) atomicAdd(&dst[(long)(k0 + c) * Dd + tid], sum);
        } else {
            dst[((long)s * Kk + (k0 + c)) * Dd + tid] = sum;
        }
    }
    if (tid < CODES)
        atomicAdd(&counts[k0 + tid],
                  cnt_l[tid][0] + cnt_l[tid][1] + cnt_l[tid][2] + cnt_l[tid][3]);
}

// ============================================================
// Kernel G: new_cluster_size + total (single block)
// ============================================================
__global__ __launch_bounds__(256) void ema_cs_kernel(
    const float* __restrict__ cs, const float* __restrict__ counts,
    float* __restrict__ ncs, float* __restrict__ total_ws)
{
    __shared__ float red[256];
    int tid = threadIdx.x;
    float s = 0.0f;
    #pragma unroll
    for (int i = 0; i < 8; ++i) {
        int k = tid + i * 256;
        float v = cs[k] * DECAY + OMD * counts[k];
        ncs[k] = v;
        s += v;
    }
    red[tid] = s;
    __syncthreads();
    #pragma unroll
    for (int off = 128; off >= 1; off >>= 1) {
        if (tid < off) red[tid] += red[tid + off];
        __syncthreads();
    }
    if (tid == 0) total_ws[0] = red[0];
}

// ============================================================
// Kernel H: combine partials -> embed_sum; nea; ne.
// ============================================================
__global__ __launch_bounds__(256) void nea_ne_kernel(
    const float* __restrict__ ea, const float* __restrict__ partials,
    int nparts, const float* __restrict__ ncs, const float* __restrict__ total_ws,
    float* __restrict__ nea, float* __restrict__ ne)
{
    long g = ((long)blockIdx.x * 256 + threadIdx.x) * 4;
    int  k = (int)(g >> 8);
    int  d = (int)(g & 255);

    float4 sv = {0.f, 0.f, 0.f, 0.f};
    for (int p = 0; p < nparts; ++p) {
        float4 pv = *(const float4*)&partials[((long)p * Kk + k) * Dd + d];
        sv.x += pv.x; sv.y += pv.y; sv.z += pv.z; sv.w += pv.w;
    }

    float4 av = *(const float4*)&ea[g];
    float4 out_nea;
    out_nea.x = av.x * DECAY + OMD * sv.x;
    out_nea.y = av.y * DECAY + OMD * sv.y;
    out_nea.z = av.z * DECAY + OMD * sv.z;
    out_nea.w = av.w * DECAY + OMD * sv.w;
    *(float4*)&nea[g] = out_nea;

    float total = total_ws[0];
    float sm = (ncs[k] + EPSF) / (total + EPSF * (float)Kk) * total;
    float inv = 1.0f / sm;
    float4 out_ne;
    out_ne.x = out_nea.x * inv;
    out_ne.y = out_nea.y * inv;
    out_ne.z = out_nea.z * inv;
    out_ne.w = out_nea.w * inv;
    *(float4*)&ne[g] = out_ne;
}

// ============================================================
extern "C" void kernel_launch(void* const* d_in, const int* in_sizes, int n_in,
                              void* d_out, int out_size, void* d_ws, size_t ws_size,
                              hipStream_t stream)
{
    const float* x     = (const float*)d_in[0];
    const float* embed = (const float*)d_in[1];
    const float* cs    = (const float*)d_in[2];
    const float* ea    = (const float*)d_in[3];

    float* out   = (float*)d_out;
    float* quant = out + OUT_QUANT;
    float* ind_f = out + OUT_IND;
    float* ncs   = out + OUT_NCS;
    float* nea   = out + OUT_NEA;
    float* ne    = out + OUT_NE;

    float* ws     = (float*)d_ws;
    float* counts = ws + WS_COUNTS;
    float* total  = ws + WS_TOTAL;
    float* ee     = ws + WS_EE;
    float* big    = ws + WS_BIG;     // embed_sum (atomic) or partials (ws path)

    // scratch inside d_out
    ushort* e_h = (ushort*)(out + OUT_NEA);     // 1MB fp16, nea region
    int*    qb  = (int*)(out + OUT_NE);

    const size_t need_partials =
        (size_t)(WS_BIG + (long)PARTS * Kk * Dd) * sizeof(float) + 1024;
    const bool use_ws_partials = ws_size >= need_partials;

    hipMemsetAsync(counts, 0, Kk * sizeof(float), stream);
    if (!use_ws_partials)
        hipMemsetAsync(big, 0, (size_t)Kk * Dd * sizeof(float), stream);

    convert_e_kernel<<<Kk / 4, 256, 0, stream>>>(embed, e_h, ee, qb);
    pass1_kernel<<<Nn / 64, 256, 0, stream>>>(x, e_h, embed, ee, ind_f, quant, qb);
    pass2_kernel<<<512, 256, 0, stream>>>(x, embed, ee, qb, ind_f, quant);
    if (use_ws_partials)
        segsum_kernel<0><<<(Kk / CODES) * PARTS, 256, 0, stream>>>(x, ind_f, big, counts);
    else
        segsum_kernel<1><<<(Kk / CODES) * PARTS, 256, 0, stream>>>(x, ind_f, big, counts);
    ema_cs_kernel<<<1, 256, 0, stream>>>(cs, counts, ncs, total);
    nea_ne_kernel<<<(Kk * Dd / 4) / 256, 256, 0, stream>>>(
        ea, big, use_ws_partials ? PARTS : 1, ncs, total, nea, ne);
}